// Round 1
// baseline (614.100 us; speedup 1.0000x reference)
//
#include <hip/hip_runtime.h>

// RGCN basis-decomposition layer, MI355X (gfx950).
//
// Algebra: the reference's torch-.view quirk reduces exactly to
//   U[n][k*4+b] = sum_{j<8} h[n][k*8+j] * w_comp[j][b]        (fold, [N,128])
//   msg_e       = U[src_e] @ Bv[etype_e]                       (Bv = basis viewed [8][128][256])
//   out         = relu(segment_sum(msg, dst) + bias)
// We pre-aggregate: S[r][dst] += U[src] per edge (128-wide fp32 atomics),
// then out = relu(sum_r S[r] @ Bv[r] + bias) as a dense GEMM (10.5 GFLOP).

#define N_NODES  20000
#define N_EDGES  320000
#define IN_DIM   256
#define OUT_DIM  256
#define NUM_RELS 8
#define KDIM     128      // folded inner dim = 32 groups * 4 bases
#define M_PAD    20032    // 313 * 64, so GEMM tiles load without guards

// ---------------------------------------------------------------- fold ----
__global__ __launch_bounds__(256)
void fold_kernel(const float* __restrict__ h,
                 const float* __restrict__ w_comp,
                 float* __restrict__ U) {
    int gid = blockIdx.x * 256 + threadIdx.x;   // over N_NODES*KDIM
    int n  = gid >> 7;
    int kb = gid & 127;
    int k = kb >> 2, b = kb & 3;
    const float* hp = h + (size_t)n * IN_DIM + k * 8;
    float acc = 0.f;
#pragma unroll
    for (int j = 0; j < 8; ++j) acc += hp[j] * w_comp[j * 4 + b];
    U[gid] = acc;
}

// -------------------------------------------------------------- scatter ----
// One wave per edge: 64 lanes x float2 = the 128-wide U row.
// filter < 0: S indexed [r][dst]; filter >= 0: only edges of that relation,
// S indexed [dst] (small-workspace fallback).
__global__ __launch_bounds__(256)
void scatter_kernel(const float* __restrict__ U,
                    const int* __restrict__ src,
                    const int* __restrict__ dst,
                    const int* __restrict__ et,
                    float* __restrict__ S, int filter) {
    int e    = blockIdx.x * 4 + (threadIdx.x >> 6);
    int lane = threadIdx.x & 63;
    int r = et[e];
    if (filter >= 0 && r != filter) return;
    int s = src[e], d = dst[e];
    int rsel = (filter >= 0) ? 0 : r;
    float2 u = *(const float2*)(U + (size_t)s * KDIM + lane * 2);
    float* p = S + (((size_t)rsel * M_PAD + d) << 7) + lane * 2;
    unsafeAtomicAdd(p,     u.x);   // global_atomic_add_f32
    unsafeAtomicAdd(p + 1, u.y);
}

// ----------------------------------------------------------------- gemm ----
// out[n][o] (+)= sum_{r<r_count} S[r][n][:] @ basis[r][:][o]
// Block: 256 threads = 16 (tn) x 16 (to); each thread owns a 4n x 4o tile.
// Tile: 64 nodes x 64 outs. S tile staged in LDS (row stride 132 floats to
// break the 512-word bank stride). basis rows read from L2 (1 MB, hot).
// flags: bit0 = accumulate into out, bit1 = apply bias+relu epilogue.
__global__ __launch_bounds__(256)
void gemm_kernel(const float* __restrict__ S, int r_count,
                 const float* __restrict__ basis,
                 const float* __restrict__ bias,
                 float* __restrict__ out, int flags) {
    __shared__ float s_tile[64][KDIM + 4];
    int n0 = blockIdx.x * 64;
    int o0 = blockIdx.y * 64;
    int t  = threadIdx.x;
    int tn = t >> 4, to = t & 15;
    int ocol = o0 + to * 4;

    float acc[4][4];
#pragma unroll
    for (int i = 0; i < 4; ++i)
#pragma unroll
        for (int j = 0; j < 4; ++j) acc[i][j] = 0.f;

    for (int r = 0; r < r_count; ++r) {
        // stage S[r][n0 .. n0+64)[0..128) -> LDS, coalesced float4
        const float4* gs = (const float4*)(S + (((size_t)r * M_PAD + n0) << 7));
#pragma unroll
        for (int i = 0; i < 8; ++i) {
            int f   = t + i * 256;        // float4 index in [0, 2048)
            int row = f >> 5, c4 = f & 31;
            float4 v = gs[(size_t)row * 32 + c4];
            *(float4*)&s_tile[row][c4 * 4] = v;
        }
        __syncthreads();

        const float* bp = basis + (size_t)r * (KDIM * OUT_DIM) + ocol;
#pragma unroll 2
        for (int k = 0; k < KDIM; k += 4) {
            float4 b0 = *(const float4*)(bp + (size_t)(k + 0) * OUT_DIM);
            float4 b1 = *(const float4*)(bp + (size_t)(k + 1) * OUT_DIM);
            float4 b2 = *(const float4*)(bp + (size_t)(k + 2) * OUT_DIM);
            float4 b3 = *(const float4*)(bp + (size_t)(k + 3) * OUT_DIM);
#pragma unroll
            for (int nn = 0; nn < 4; ++nn) {
                float4 a = *(const float4*)&s_tile[tn * 4 + nn][k];
                acc[nn][0] += a.x * b0.x + a.y * b1.x + a.z * b2.x + a.w * b3.x;
                acc[nn][1] += a.x * b0.y + a.y * b1.y + a.z * b2.y + a.w * b3.y;
                acc[nn][2] += a.x * b0.z + a.y * b1.z + a.z * b2.z + a.w * b3.z;
                acc[nn][3] += a.x * b0.w + a.y * b1.w + a.z * b2.w + a.w * b3.w;
            }
        }
        __syncthreads();
    }

    float4 bb = make_float4(0.f, 0.f, 0.f, 0.f);
    if (flags & 2) bb = *(const float4*)(bias + ocol);
#pragma unroll
    for (int nn = 0; nn < 4; ++nn) {
        int n = n0 + tn * 4 + nn;
        if (n >= N_NODES) continue;
        float* op = out + (size_t)n * OUT_DIM + ocol;
        float v0 = acc[nn][0], v1 = acc[nn][1], v2 = acc[nn][2], v3 = acc[nn][3];
        if (flags & 1) {
            float4 p = *(const float4*)op;
            v0 += p.x; v1 += p.y; v2 += p.z; v3 += p.w;
        }
        if (flags & 2) {
            v0 = fmaxf(v0 + bb.x, 0.f);
            v1 = fmaxf(v1 + bb.y, 0.f);
            v2 = fmaxf(v2 + bb.z, 0.f);
            v3 = fmaxf(v3 + bb.w, 0.f);
        }
        float4 v = make_float4(v0, v1, v2, v3);
        *(float4*)op = v;
    }
}

// --------------------------------------------------------------- launch ----
extern "C" void kernel_launch(void* const* d_in, const int* in_sizes, int n_in,
                              void* d_out, int out_size, void* d_ws, size_t ws_size,
                              hipStream_t stream) {
    const float* h      = (const float*)d_in[0];
    const float* basis  = (const float*)d_in[1];   // viewed as [8][128][256]
    const float* w_comp = (const float*)d_in[2];
    const float* bias   = (const float*)d_in[3];
    const int*   src    = (const int*)d_in[4];
    const int*   dst    = (const int*)d_in[5];
    const int*   etype  = (const int*)d_in[6];
    float*       out    = (float*)d_out;

    char*  ws      = (char*)d_ws;
    float* U       = (float*)ws;                       // N_NODES*KDIM*4 = 10,240,000 B
    size_t u_bytes = (size_t)N_NODES * KDIM * 4;
    float* S       = (float*)(ws + u_bytes);
    size_t s_big   = (size_t)NUM_RELS * M_PAD * KDIM * 4;   // 82,051,072 B
    size_t s_one   = (size_t)M_PAD * KDIM * 4;

    fold_kernel<<<(N_NODES * KDIM) / 256, 256, 0, stream>>>(h, w_comp, U);

    dim3 ggrid(313, 4);
    if (ws_size >= u_bytes + s_big) {
        hipMemsetAsync(S, 0, s_big, stream);
        scatter_kernel<<<N_EDGES / 4, 256, 0, stream>>>(U, src, dst, etype, S, -1);
        gemm_kernel<<<ggrid, 256, 0, stream>>>(S, NUM_RELS, basis, bias, out, 2);
    } else {
        // small-workspace fallback: one relation at a time
        for (int r = 0; r < NUM_RELS; ++r) {
            hipMemsetAsync(S, 0, s_one, stream);
            scatter_kernel<<<N_EDGES / 4, 256, 0, stream>>>(U, src, dst, etype, S, r);
            int flags = (r > 0 ? 1 : 0) | (r == NUM_RELS - 1 ? 2 : 0);
            gemm_kernel<<<ggrid, 256, 0, stream>>>(S, 1, basis + (size_t)r * KDIM * OUT_DIM,
                                                   bias, out, flags);
        }
    }
}

// Round 2
// 306.305 us; speedup vs baseline: 2.0049x; 2.0049x over previous
//
#include <hip/hip_runtime.h>

// RGCN basis-decomposition layer, MI355X (gfx950).
//
// Algebra (torch-.view quirk folded out):
//   U[n][k*4+b] = sum_{j<8} h[n][k*8+j] * w_comp[j][b]     (fold, [N,128], bf16)
//   S[r][d]     = sum_{e: dst=d, et=r} U[src_e]            (CSR aggregate, no atomics)
//   out         = relu(sum_r S[r] @ Bv[r] + bias)          (bf16 MFMA GEMM, K=8*128)
// Bv = basis raw-reinterpreted [8][128][256]; Bt = its bf16 transpose [256][1024].

#define N_NODES  20000
#define N_EDGES  320000
#define IN_DIM   256
#define OUT_DIM  256
#define NUM_RELS 8
#define KDIM     128
#define M_PAD    20032          // 313 * 64

typedef __attribute__((ext_vector_type(8)))  short short8;
typedef __attribute__((ext_vector_type(16))) float float16v;

static __device__ __forceinline__ unsigned f2bf_rne(float x) {
    unsigned u = __float_as_uint(x);
    return (u + 0x7fffu + ((u >> 16) & 1u)) >> 16;
}
static __device__ __forceinline__ float bf2f(unsigned b) {
    return __uint_as_float(b << 16);
}

// ---------------------------------------------------------------- fold ----
__global__ __launch_bounds__(256)
void fold_kernel(const float* __restrict__ h,
                 const float* __restrict__ w_comp,
                 unsigned short* __restrict__ U) {
    int gid = blockIdx.x * 256 + threadIdx.x;   // over N_NODES*KDIM
    int n  = gid >> 7;
    int kb = gid & 127;
    int k = kb >> 2, b = kb & 3;
    const float* hp = h + (size_t)n * IN_DIM + k * 8;
    float acc = 0.f;
#pragma unroll
    for (int j = 0; j < 8; ++j) acc += hp[j] * w_comp[j * 4 + b];
    U[gid] = (unsigned short)f2bf_rne(acc);
}

// ------------------------------------------------------------ CSR build ----
__global__ __launch_bounds__(256)
void count_kernel(const int* __restrict__ dst, int* __restrict__ cnt) {
    int e = blockIdx.x * 256 + threadIdx.x;
    atomicAdd(&cnt[dst[e]], 1);
}

// single block, 256 threads: exclusive scan of cnt[20000] -> offs, cursor
__global__ __launch_bounds__(256)
void scan_kernel(const int* __restrict__ cnt,
                 int* __restrict__ offs, int* __restrict__ cursor) {
    __shared__ int buf[256];
    __shared__ int carry;
    int t = threadIdx.x;
    if (t == 0) carry = 0;
    __syncthreads();
    for (int base = 0; base < N_NODES; base += 256) {
        int i = base + t;
        int v = (i < N_NODES) ? cnt[i] : 0;
        buf[t] = v;
        __syncthreads();
        for (int off = 1; off < 256; off <<= 1) {
            int x = (t >= off) ? buf[t - off] : 0;
            __syncthreads();
            buf[t] += x;
            __syncthreads();
        }
        int excl = buf[t] - v;
        if (i < N_NODES) { offs[i] = carry + excl; cursor[i] = carry + excl; }
        __syncthreads();
        if (t == 255) carry += buf[255];
        __syncthreads();
    }
    if (t == 0) offs[N_NODES] = carry;
}

__global__ __launch_bounds__(256)
void fill_kernel(const int* __restrict__ src, const int* __restrict__ dst,
                 const int* __restrict__ et,
                 int* __restrict__ cursor, int* __restrict__ elist) {
    int e = blockIdx.x * 256 + threadIdx.x;
    int d = dst[e];
    int p = atomicAdd(&cursor[d], 1);
    elist[p] = src[e] | (et[e] << 16);
}

// ------------------------------------------------------------ aggregate ----
// One wave per dst node. 8 relation rows accumulated in registers
// (8 x float2 per lane = 128 floats per row pair-slot), written as bf16.
__global__ __launch_bounds__(256)
void aggregate_kernel(const unsigned short* __restrict__ U,
                      const int* __restrict__ offs,
                      const int* __restrict__ elist,
                      unsigned int* __restrict__ S) {  // S as uint (2 bf16)
    int wid  = threadIdx.x >> 6;
    int lane = threadIdx.x & 63;
    int d = blockIdx.x * 4 + wid;          // < 20032
    float2 acc[NUM_RELS];
#pragma unroll
    for (int r = 0; r < NUM_RELS; ++r) { acc[r].x = 0.f; acc[r].y = 0.f; }

    if (d < N_NODES) {
        int beg = offs[d], end = offs[d + 1];
        for (int i = beg; i < end; ++i) {
            int e = elist[i];
            int s = e & 0xffff;
            int r = __builtin_amdgcn_readfirstlane(e >> 16);
            unsigned u = *(const unsigned*)(U + ((size_t)s << 7) + lane * 2);
            float fx = bf2f(u & 0xffffu), fy = bf2f(u >> 16);
            switch (r) {
                case 0: acc[0].x += fx; acc[0].y += fy; break;
                case 1: acc[1].x += fx; acc[1].y += fy; break;
                case 2: acc[2].x += fx; acc[2].y += fy; break;
                case 3: acc[3].x += fx; acc[3].y += fy; break;
                case 4: acc[4].x += fx; acc[4].y += fy; break;
                case 5: acc[5].x += fx; acc[5].y += fy; break;
                case 6: acc[6].x += fx; acc[6].y += fy; break;
                default: acc[7].x += fx; acc[7].y += fy; break;
            }
        }
    }
#pragma unroll
    for (int r = 0; r < NUM_RELS; ++r) {
        unsigned p = f2bf_rne(acc[r].x) | (f2bf_rne(acc[r].y) << 16);
        S[(((size_t)r * M_PAD + d) << 6) + lane] = p;
    }
}

// -------------------------------------------------------------- B prep ----
// Bt[o][r*128+k] = bf16(basis[(r*128+k)*256 + o])   (transposed, bf16)
__global__ __launch_bounds__(256)
void bprep_kernel(const float* __restrict__ basis,
                  unsigned short* __restrict__ Bt) {
    int tid = blockIdx.x * 256 + threadIdx.x;   // 0 .. 256*1024-1
    int o = tid >> 10, kk = tid & 1023;
    Bt[(size_t)o * 1024 + kk] = (unsigned short)f2bf_rne(basis[(size_t)kk * 256 + o]);
}

// ----------------------------------------------------------------- gemm ----
// out[n][o] = relu(sum_{r,k} S[r][n][k] * Bt[o][r*128+k] + bias[o])
// Block 256 thr = 4 waves, C tile 64 rows x 128 cols, grid (313, 2).
// Wave w: rows (w&1)*32, cols (w>>1)*64 -> two 32x32 MFMA tiles, 32 acc VGPRs.
// A staged in LDS (row stride 136 bf16: 16B-aligned, bank-balanced).
__global__ __launch_bounds__(256)
void gemm_kernel(const unsigned short* __restrict__ S,
                 const unsigned short* __restrict__ Bt,
                 const float* __restrict__ bias,
                 float* __restrict__ out) {
    __shared__ unsigned short At[64][136];
    int t = threadIdx.x;
    int w = t >> 6, lane = t & 63;
    int ln = lane & 31, hi = lane >> 5;
    int n0 = blockIdx.x * 64;
    int row0 = (w & 1) * 32;
    int cbase = blockIdx.y * 128 + (w >> 1) * 64;   // two tiles: cbase, cbase+32

    float16v a0 = {}, a1 = {};

    for (int r = 0; r < NUM_RELS; ++r) {
        const unsigned short* Ssl = S + (((size_t)r * M_PAD + n0) << 7);
#pragma unroll
        for (int i = 0; i < 4; ++i) {
            int idx = i * 256 + t;             // 1024 x 16B
            int row = idx >> 4, q = idx & 15;
            uint4 v = *(const uint4*)(Ssl + ((size_t)row << 7) + q * 8);
            *(uint4*)&At[row][q * 8] = v;
        }
        __syncthreads();

        const unsigned short* bp0 = Bt + (size_t)(cbase + ln) * 1024 + r * KDIM + hi * 8;
        const unsigned short* bp1 = bp0 + (size_t)32 * 1024;
#pragma unroll
        for (int ks = 0; ks < 8; ++ks) {
            short8 a = *(const short8*)&At[row0 + ln][ks * 16 + hi * 8];
            short8 b0 = *(const short8*)(bp0 + ks * 16);
            short8 b1 = *(const short8*)(bp1 + ks * 16);
            a0 = __builtin_amdgcn_mfma_f32_32x32x16_bf16(a, b0, a0, 0, 0, 0);
            a1 = __builtin_amdgcn_mfma_f32_32x32x16_bf16(a, b1, a1, 0, 0, 0);
        }
        __syncthreads();
    }

    // epilogue: C/D layout col=lane&31, row=(reg&3)+8*(reg>>2)+4*(lane>>5)
    float bias0 = bias[cbase + ln];
    float bias1 = bias[cbase + 32 + ln];
#pragma unroll
    for (int reg = 0; reg < 16; ++reg) {
        int row = (reg & 3) + 8 * (reg >> 2) + 4 * hi;
        int n = n0 + row0 + row;
        if (n < N_NODES) {
            float v0 = fmaxf(a0[reg] + bias0, 0.f);
            float v1 = fmaxf(a1[reg] + bias1, 0.f);
            out[(size_t)n * OUT_DIM + cbase + ln]      = v0;
            out[(size_t)n * OUT_DIM + cbase + 32 + ln] = v1;
        }
    }
}

// --------------------------------------------------------------- launch ----
extern "C" void kernel_launch(void* const* d_in, const int* in_sizes, int n_in,
                              void* d_out, int out_size, void* d_ws, size_t ws_size,
                              hipStream_t stream) {
    const float* h      = (const float*)d_in[0];
    const float* basis  = (const float*)d_in[1];
    const float* w_comp = (const float*)d_in[2];
    const float* bias   = (const float*)d_in[3];
    const int*   src    = (const int*)d_in[4];
    const int*   dst    = (const int*)d_in[5];
    const int*   etype  = (const int*)d_in[6];
    float*       out    = (float*)d_out;

    char* ws = (char*)d_ws;
    size_t off = 0;
    unsigned short* U   = (unsigned short*)(ws + off); off += (size_t)N_NODES * KDIM * 2;        // 5.12 MB
    unsigned int*   S   = (unsigned int*)(ws + off);   off += (size_t)NUM_RELS * M_PAD * KDIM * 2; // 41.0 MB
    unsigned short* Bt  = (unsigned short*)(ws + off); off += (size_t)OUT_DIM * 1024 * 2;        // 0.52 MB
    int* cnt    = (int*)(ws + off); off += (size_t)M_PAD * 4;
    int* offs   = (int*)(ws + off); off += (size_t)(M_PAD + 16) * 4;
    int* cursor = (int*)(ws + off); off += (size_t)M_PAD * 4;
    int* elist  = (int*)(ws + off); off += (size_t)N_EDGES * 4;

    hipMemsetAsync(cnt, 0, (size_t)N_NODES * 4, stream);

    fold_kernel<<<(N_NODES * KDIM) / 256, 256, 0, stream>>>(h, w_comp, U);
    count_kernel<<<N_EDGES / 256, 256, 0, stream>>>(dst, cnt);
    scan_kernel<<<1, 256, 0, stream>>>(cnt, offs, cursor);
    fill_kernel<<<N_EDGES / 256, 256, 0, stream>>>(src, dst, etype, cursor, elist);
    aggregate_kernel<<<M_PAD / 4, 256, 0, stream>>>(U, offs, elist, S);
    bprep_kernel<<<(OUT_DIM * 1024) / 256, 256, 0, stream>>>(basis, Bt);

    dim3 ggrid(M_PAD / 64, 2);
    gemm_kernel<<<ggrid, 256, 0, stream>>>((const unsigned short*)S, Bt, bias, out);
}

// Round 3
// 198.517 us; speedup vs baseline: 3.0934x; 1.5430x over previous
//
#include <hip/hip_runtime.h>

// RGCN basis-decomposition layer, MI355X (gfx950).
//
// Algebra (torch-.view quirk folded out):
//   U[n][k*4+b] = sum_{j<8} h[n][k*8+j] * w_comp[j][b]     (fold, [N,128], bf16)
//   S[r][d]     = sum_{e: dst=d, et=r} U[src_e]            (bucketed aggregate)
//   out         = relu(sum_r S[r] @ Bv[r] + bias)          (bf16 MFMA GEMM, K=8*128)
// Bv = basis raw-reinterpreted [8][128][256]; Bt = its bf16 transpose [256][1024].
//
// R3: replaced count+scan(90us single-block!)+fill CSR build with a
// fixed-capacity bucket table (avg deg 16, CAP=96 => overflow prob < 1e-40);
// GEMM C-tile 32x256 so S is fetched exactly once (was twice).

#define N_NODES  20000
#define N_EDGES  320000
#define IN_DIM   256
#define OUT_DIM  256
#define NUM_RELS 8
#define KDIM     128
#define M_PAD    20032          // 626 * 32
#define CAP      96             // bucket capacity per dst node

typedef __attribute__((ext_vector_type(8)))  short short8;
typedef __attribute__((ext_vector_type(16))) float float16v;

static __device__ __forceinline__ unsigned f2bf_rne(float x) {
    unsigned u = __float_as_uint(x);
    return (u + 0x7fffu + ((u >> 16) & 1u)) >> 16;
}
static __device__ __forceinline__ float bf2f(unsigned b) {
    return __uint_as_float(b << 16);
}

// ---------------------------------------------------------------- fold ----
__global__ __launch_bounds__(256)
void fold_kernel(const float* __restrict__ h,
                 const float* __restrict__ w_comp,
                 unsigned short* __restrict__ U) {
    int gid = blockIdx.x * 256 + threadIdx.x;   // over N_NODES*KDIM
    int n  = gid >> 7;
    int kb = gid & 127;
    int k = kb >> 2, b = kb & 3;
    const float* hp = h + (size_t)n * IN_DIM + k * 8;
    float acc = 0.f;
#pragma unroll
    for (int j = 0; j < 8; ++j) acc += hp[j] * w_comp[j * 4 + b];
    U[gid] = (unsigned short)f2bf_rne(acc);
}

// --------------------------------------------------------- bucket build ----
__global__ __launch_bounds__(256)
void fill_kernel(const int* __restrict__ src, const int* __restrict__ dst,
                 const int* __restrict__ et,
                 int* __restrict__ cnt, int* __restrict__ bucket) {
    int e = blockIdx.x * 256 + threadIdx.x;
    int d = dst[e];
    int p = atomicAdd(&cnt[d], 1);
    if (p < CAP) bucket[(size_t)d * CAP + p] = src[e] | (et[e] << 16);
}

// ------------------------------------------------------------ aggregate ----
// One wave per dst node; 8 relation rows accumulated in registers
// (8 x float2 per lane = 128 floats per relation), written as bf16.
__global__ __launch_bounds__(256)
void aggregate_kernel(const unsigned short* __restrict__ U,
                      const int* __restrict__ cnt,
                      const int* __restrict__ bucket,
                      unsigned int* __restrict__ S) {  // S as uint (2 bf16)
    int wid  = threadIdx.x >> 6;
    int lane = threadIdx.x & 63;
    int d = blockIdx.x * 4 + wid;          // < 20032
    float2 acc[NUM_RELS];
#pragma unroll
    for (int r = 0; r < NUM_RELS; ++r) { acc[r].x = 0.f; acc[r].y = 0.f; }

    if (d < N_NODES) {
        int n = cnt[d];
        if (n > CAP) n = CAP;
        const int* bp = bucket + (size_t)d * CAP;
        for (int i = 0; i < n; ++i) {
            int e = bp[i];
            int s = e & 0xffff;
            int r = __builtin_amdgcn_readfirstlane(e >> 16);
            unsigned u = *(const unsigned*)(U + ((size_t)s << 7) + lane * 2);
            float fx = bf2f(u & 0xffffu), fy = bf2f(u >> 16);
            switch (r) {
                case 0: acc[0].x += fx; acc[0].y += fy; break;
                case 1: acc[1].x += fx; acc[1].y += fy; break;
                case 2: acc[2].x += fx; acc[2].y += fy; break;
                case 3: acc[3].x += fx; acc[3].y += fy; break;
                case 4: acc[4].x += fx; acc[4].y += fy; break;
                case 5: acc[5].x += fx; acc[5].y += fy; break;
                case 6: acc[6].x += fx; acc[6].y += fy; break;
                default: acc[7].x += fx; acc[7].y += fy; break;
            }
        }
    }
#pragma unroll
    for (int r = 0; r < NUM_RELS; ++r) {
        unsigned p = f2bf_rne(acc[r].x) | (f2bf_rne(acc[r].y) << 16);
        S[(((size_t)r * M_PAD + d) << 6) + lane] = p;
    }
}

// -------------------------------------------------------------- B prep ----
// Bt[o][r*128+k] = bf16(basis[(r*128+k)*256 + o])   (transposed, bf16)
__global__ __launch_bounds__(256)
void bprep_kernel(const float* __restrict__ basis,
                  unsigned short* __restrict__ Bt) {
    int tid = blockIdx.x * 256 + threadIdx.x;   // 0 .. 256*1024-1
    int o = tid >> 10, kk = tid & 1023;
    Bt[(size_t)o * 1024 + kk] = (unsigned short)f2bf_rne(basis[(size_t)kk * 256 + o]);
}

// ----------------------------------------------------------------- gemm ----
// out[n][o] = relu(sum_{r,k} S[r][n][k] * Bt[o][r*128+k] + bias[o])
// Block 256 thr = 4 waves, C tile 32 rows x 256 cols, grid 626. Each S
// element is staged exactly once. Wave w: cols w*64 .. w*64+63 -> two
// 32x32 MFMA tiles (32 acc VGPRs). A staged in LDS, row stride 136 bf16.
__global__ __launch_bounds__(256)
void gemm_kernel(const unsigned short* __restrict__ S,
                 const unsigned short* __restrict__ Bt,
                 const float* __restrict__ bias,
                 float* __restrict__ out) {
    __shared__ unsigned short At[32][136];
    int t = threadIdx.x;
    int w = t >> 6, lane = t & 63;
    int ln = lane & 31, hi = lane >> 5;
    int n0 = blockIdx.x * 32;
    int c0 = w * 64;                       // wave's first col tile

    float16v a0 = {}, a1 = {};

    for (int r = 0; r < NUM_RELS; ++r) {
        // stage S[r][n0..n0+32)[0..128) -> LDS: 512 x 16B, 2 per thread
        const unsigned short* Ssl = S + (((size_t)r * M_PAD + n0) << 7);
#pragma unroll
        for (int i = 0; i < 2; ++i) {
            int idx = i * 256 + t;             // [0, 512)
            int row = idx >> 4, q = idx & 15;
            uint4 v = *(const uint4*)(Ssl + ((size_t)row << 7) + q * 8);
            *(uint4*)&At[row][q * 8] = v;
        }
        __syncthreads();

        const unsigned short* bp0 = Bt + (size_t)(c0 + ln) * 1024 + r * KDIM + hi * 8;
        const unsigned short* bp1 = bp0 + (size_t)32 * 1024;
#pragma unroll
        for (int ks = 0; ks < 8; ++ks) {
            short8 a  = *(const short8*)&At[ln][ks * 16 + hi * 8];
            short8 b0 = *(const short8*)(bp0 + ks * 16);
            short8 b1 = *(const short8*)(bp1 + ks * 16);
            a0 = __builtin_amdgcn_mfma_f32_32x32x16_bf16(a, b0, a0, 0, 0, 0);
            a1 = __builtin_amdgcn_mfma_f32_32x32x16_bf16(a, b1, a1, 0, 0, 0);
        }
        __syncthreads();
    }

    // epilogue: C/D layout col=lane&31, row=(reg&3)+8*(reg>>2)+4*(lane>>5)
    float bias0 = bias[c0 + ln];
    float bias1 = bias[c0 + 32 + ln];
#pragma unroll
    for (int reg = 0; reg < 16; ++reg) {
        int row = (reg & 3) + 8 * (reg >> 2) + 4 * hi;
        int n = n0 + row;
        if (n < N_NODES) {
            out[(size_t)n * OUT_DIM + c0 + ln]      = fmaxf(a0[reg] + bias0, 0.f);
            out[(size_t)n * OUT_DIM + c0 + 32 + ln] = fmaxf(a1[reg] + bias1, 0.f);
        }
    }
}

// --------------------------------------------------------------- launch ----
extern "C" void kernel_launch(void* const* d_in, const int* in_sizes, int n_in,
                              void* d_out, int out_size, void* d_ws, size_t ws_size,
                              hipStream_t stream) {
    const float* h      = (const float*)d_in[0];
    const float* basis  = (const float*)d_in[1];
    const float* w_comp = (const float*)d_in[2];
    const float* bias   = (const float*)d_in[3];
    const int*   src    = (const int*)d_in[4];
    const int*   dst    = (const int*)d_in[5];
    const int*   etype  = (const int*)d_in[6];
    float*       out    = (float*)d_out;

    char* ws = (char*)d_ws;
    size_t off = 0;
    unsigned short* U   = (unsigned short*)(ws + off); off += (size_t)N_NODES * KDIM * 2;          // 5.12 MB
    unsigned int*   S   = (unsigned int*)(ws + off);   off += (size_t)NUM_RELS * M_PAD * KDIM * 2; // 41.0 MB
    unsigned short* Bt  = (unsigned short*)(ws + off); off += (size_t)OUT_DIM * 1024 * 2;          // 0.52 MB
    int* cnt    = (int*)(ws + off); off += (size_t)M_PAD * 4;                                      // 80 KB
    int* bucket = (int*)(ws + off); off += (size_t)M_PAD * CAP * 4;                                // 7.7 MB

    hipMemsetAsync(cnt, 0, (size_t)N_NODES * 4, stream);

    fold_kernel<<<(N_NODES * KDIM) / 256, 256, 0, stream>>>(h, w_comp, U);
    fill_kernel<<<N_EDGES / 256, 256, 0, stream>>>(src, dst, etype, cnt, bucket);
    bprep_kernel<<<(OUT_DIM * 1024) / 256, 256, 0, stream>>>(basis, Bt);
    aggregate_kernel<<<M_PAD / 4, 256, 0, stream>>>(U, cnt, bucket, S);

    gemm_kernel<<<M_PAD / 32, 256, 0, stream>>>((const unsigned short*)S, Bt, bias, out);
}

// Round 4
// 190.022 us; speedup vs baseline: 3.2317x; 1.0447x over previous
//
#include <hip/hip_runtime.h>

// RGCN basis-decomposition layer, MI355X (gfx950).
//
// Algebra (torch-.view quirk folded out):
//   U[n][k*4+b] = sum_{j<8} h[n][k*8+j] * w_comp[j][b]     (fold, [N,128], bf16)
//   S[r][d]     = sum_{e: dst=d, et=r} U[src_e]            (bucketed aggregate)
//   out         = relu(sum_r S[r] @ Bv[r] + bias)          (bf16 MFMA GEMM, K=8*128)
// Bv = basis raw-reinterpreted [8][128][256]; Bt = its bf16 transpose [256][1024].
//
// R4: prep stages fused into one dispatch (fold | fill | basis-transpose);
// GEMM: 1 MFMA tile/wave, 512-thr blocks -> 5008 waves (was 2504 @ 19% occ),
// next-relation A-tile prefetched through VGPRs; aggregate reads bucket int4
// for 4-deep gather MLP.

#define N_NODES  20000
#define N_EDGES  320000
#define IN_DIM   256
#define OUT_DIM  256
#define NUM_RELS 8
#define KDIM     128
#define M_PAD    20032          // 626 * 32
#define CAP      96             // bucket capacity per dst node (avg deg 16)

#define FOLD_BLOCKS 2500        // N_NODES*32 / 256
#define FILL_BLOCKS 1250        // N_EDGES / 256
#define BT_BLOCKS   64          // (256/64) * (1024/64)

typedef __attribute__((ext_vector_type(8)))  short short8;
typedef __attribute__((ext_vector_type(16))) float float16v;

static __device__ __forceinline__ unsigned f2bf_rne(float x) {
    unsigned u = __float_as_uint(x);
    return (u + 0x7fffu + ((u >> 16) & 1u)) >> 16;
}
static __device__ __forceinline__ float bf2f(unsigned b) {
    return __uint_as_float(b << 16);
}

// ----------------------------------------------------------------- prep ----
// blockIdx [0, FOLD)              : fold h -> U (bf16)
// blockIdx [FOLD, FOLD+FILL)      : bucket-fill edges by dst
// blockIdx [FOLD+FILL, ...+BT)    : basis -> Bt bf16 transpose via LDS
__global__ __launch_bounds__(256)
void prep_kernel(const float* __restrict__ h, const float* __restrict__ w_comp,
                 unsigned short* __restrict__ U,
                 const int* __restrict__ src, const int* __restrict__ dst,
                 const int* __restrict__ et,
                 int* __restrict__ cnt, int* __restrict__ bucket,
                 const float* __restrict__ basis, unsigned short* __restrict__ Bt) {
    __shared__ float tile[64][65];
    int b = blockIdx.x;
    int t = threadIdx.x;
    if (b < FOLD_BLOCKS) {
        // thread computes U[n][k*4 .. k*4+3]
        int gid = b * 256 + t;                 // over N_NODES*32
        int n = gid >> 5, k = gid & 31;
        const float* hp = h + (size_t)n * IN_DIM + k * 8;
        float4 h0 = *(const float4*)hp;
        float4 h1 = *(const float4*)(hp + 4);
        float hv[8] = {h0.x, h0.y, h0.z, h0.w, h1.x, h1.y, h1.z, h1.w};
        float a0 = 0.f, a1 = 0.f, a2 = 0.f, a3 = 0.f;
#pragma unroll
        for (int j = 0; j < 8; ++j) {
            float hj = hv[j];
            a0 += hj * w_comp[j * 4 + 0];
            a1 += hj * w_comp[j * 4 + 1];
            a2 += hj * w_comp[j * 4 + 2];
            a3 += hj * w_comp[j * 4 + 3];
        }
        uint2 p;
        p.x = f2bf_rne(a0) | (f2bf_rne(a1) << 16);
        p.y = f2bf_rne(a2) | (f2bf_rne(a3) << 16);
        *(uint2*)(U + ((size_t)n << 7) + k * 4) = p;
    } else if (b < FOLD_BLOCKS + FILL_BLOCKS) {
        int e = (b - FOLD_BLOCKS) * 256 + t;
        int d = dst[e];
        int p = atomicAdd(&cnt[d], 1);
        if (p < CAP) bucket[(size_t)d * CAP + p] = src[e] | (et[e] << 16);
    } else {
        // transpose one 64(kk) x 64(o) tile of basis into Bt[o][kk]
        int b3 = b - FOLD_BLOCKS - FILL_BLOCKS;   // [0, 64)
        int o0 = (b3 & 3) * 64, kk0 = (b3 >> 2) * 64;
        int r4 = t >> 6, c = t & 63;
#pragma unroll
        for (int it = 0; it < 16; ++it) {
            int kk = it * 4 + r4;
            tile[kk][c] = basis[(size_t)(kk0 + kk) * 256 + o0 + c];
        }
        __syncthreads();
#pragma unroll
        for (int it = 0; it < 16; ++it) {
            int oo = it * 4 + r4;
            Bt[(size_t)(o0 + oo) * 1024 + kk0 + c] = (unsigned short)f2bf_rne(tile[c][oo]);
        }
    }
}

// ------------------------------------------------------------ aggregate ----
// One wave per dst node; bucket read int4 -> 4 independent U-row gathers in
// flight. 8 relation rows accumulated fp32 in registers, written bf16.
__global__ __launch_bounds__(256)
void aggregate_kernel(const unsigned short* __restrict__ U,
                      const int* __restrict__ cnt,
                      const int* __restrict__ bucket,
                      unsigned int* __restrict__ S) {  // S as uint (2 bf16)
    int wid  = threadIdx.x >> 6;
    int lane = threadIdx.x & 63;
    int d = blockIdx.x * 4 + wid;          // < 20032
    float2 acc[NUM_RELS];
#pragma unroll
    for (int r = 0; r < NUM_RELS; ++r) { acc[r].x = 0.f; acc[r].y = 0.f; }

    if (d < N_NODES) {
        int n = cnt[d];
        if (n > CAP) n = CAP;
        const int4* bp4 = (const int4*)(bucket + (size_t)d * CAP);
        for (int i = 0; i < n; i += 4) {
            int4 e4 = bp4[i >> 2];
            int m = n - i;
            int es[4] = {e4.x, e4.y, e4.z, e4.w};
#pragma unroll
            for (int j = 0; j < 4; ++j) {
                if (j < m) {
                    int e = es[j];
                    int s = e & 0xffff;
                    int r = __builtin_amdgcn_readfirstlane(e >> 16);
                    unsigned u = *(const unsigned*)(U + ((size_t)s << 7) + lane * 2);
                    float fx = bf2f(u & 0xffffu), fy = bf2f(u >> 16);
                    switch (r) {
                        case 0: acc[0].x += fx; acc[0].y += fy; break;
                        case 1: acc[1].x += fx; acc[1].y += fy; break;
                        case 2: acc[2].x += fx; acc[2].y += fy; break;
                        case 3: acc[3].x += fx; acc[3].y += fy; break;
                        case 4: acc[4].x += fx; acc[4].y += fy; break;
                        case 5: acc[5].x += fx; acc[5].y += fy; break;
                        case 6: acc[6].x += fx; acc[6].y += fy; break;
                        default: acc[7].x += fx; acc[7].y += fy; break;
                    }
                }
            }
        }
    }
#pragma unroll
    for (int r = 0; r < NUM_RELS; ++r) {
        unsigned p = f2bf_rne(acc[r].x) | (f2bf_rne(acc[r].y) << 16);
        S[(((size_t)r * M_PAD + d) << 6) + lane] = p;
    }
}

// ----------------------------------------------------------------- gemm ----
// out[n][o] = relu(sum_{r,k} S[r][n][k] * Bt[o][r*128+k] + bias[o])
// 512 thr = 8 waves; C tile 32 rows x 256 cols; wave w -> one 32x32 MFMA
// tile at cols w*32. Grid 626 -> 5008 waves. S staged once; next relation's
// A-tile prefetched global->VGPR during the MFMA loop.
__global__ __launch_bounds__(512)
void gemm_kernel(const unsigned short* __restrict__ S,
                 const unsigned short* __restrict__ Bt,
                 const float* __restrict__ bias,
                 float* __restrict__ out) {
    __shared__ unsigned short At[32][136];
    int t = threadIdx.x;
    int w = t >> 6, lane = t & 63;
    int ln = lane & 31, hi = lane >> 5;
    int n0 = blockIdx.x * 32;
    int c0 = w * 32;

    int srow = t >> 4, sq = t & 15;        // staging: 512 x 16B = 32 rows x 256B
    const unsigned short* sbase = S + (((size_t)n0 + srow) << 7) + sq * 8;
    uint4 pre = *(const uint4*)sbase;      // r=0 A-tile fragment

    const unsigned short* bp = Bt + (size_t)(c0 + ln) * 1024 + hi * 8;
    float16v acc = {};

    for (int r = 0; r < NUM_RELS; ++r) {
        if (r > 0) __syncthreads();        // prev iter's LDS reads complete
        *(uint4*)&At[srow][sq * 8] = pre;
        __syncthreads();
        if (r + 1 < NUM_RELS)
            pre = *(const uint4*)(sbase + (((size_t)(r + 1) * M_PAD) << 7));
        const unsigned short* bpr = bp + r * KDIM;
#pragma unroll
        for (int ks = 0; ks < 8; ++ks) {
            short8 a = *(const short8*)&At[ln][ks * 16 + hi * 8];
            short8 bo = *(const short8*)(bpr + ks * 16);
            acc = __builtin_amdgcn_mfma_f32_32x32x16_bf16(a, bo, acc, 0, 0, 0);
        }
    }

    // epilogue: C/D layout col=lane&31, row=(reg&3)+8*(reg>>2)+4*(lane>>5)
    float bs = bias[c0 + ln];
#pragma unroll
    for (int reg = 0; reg < 16; ++reg) {
        int row = (reg & 3) + 8 * (reg >> 2) + 4 * hi;
        int n = n0 + row;
        if (n < N_NODES)
            out[(size_t)n * OUT_DIM + c0 + ln] = fmaxf(acc[reg] + bs, 0.f);
    }
}

// --------------------------------------------------------------- launch ----
extern "C" void kernel_launch(void* const* d_in, const int* in_sizes, int n_in,
                              void* d_out, int out_size, void* d_ws, size_t ws_size,
                              hipStream_t stream) {
    const float* h      = (const float*)d_in[0];
    const float* basis  = (const float*)d_in[1];
    const float* w_comp = (const float*)d_in[2];
    const float* bias   = (const float*)d_in[3];
    const int*   src    = (const int*)d_in[4];
    const int*   dst    = (const int*)d_in[5];
    const int*   etype  = (const int*)d_in[6];
    float*       out    = (float*)d_out;

    char* ws = (char*)d_ws;
    size_t off = 0;
    unsigned short* U   = (unsigned short*)(ws + off); off += (size_t)N_NODES * KDIM * 2;          // 5.12 MB
    unsigned int*   S   = (unsigned int*)(ws + off);   off += (size_t)NUM_RELS * M_PAD * KDIM * 2; // 41.0 MB
    unsigned short* Bt  = (unsigned short*)(ws + off); off += (size_t)OUT_DIM * 1024 * 2;          // 0.52 MB
    int* cnt    = (int*)(ws + off); off += (size_t)M_PAD * 4;                                      // 80 KB
    int* bucket = (int*)(ws + off); off += (size_t)M_PAD * CAP * 4;                                // 7.7 MB

    hipMemsetAsync(cnt, 0, (size_t)N_NODES * 4, stream);

    prep_kernel<<<FOLD_BLOCKS + FILL_BLOCKS + BT_BLOCKS, 256, 0, stream>>>(
        h, w_comp, U, src, dst, etype, cnt, bucket, basis, Bt);

    aggregate_kernel<<<M_PAD / 4, 256, 0, stream>>>(U, cnt, bucket, S);

    gemm_kernel<<<M_PAD / 32, 512, 0, stream>>>((const unsigned short*)S, Bt, bias, out);
}

// Round 5
// 152.431 us; speedup vs baseline: 4.0287x; 1.2466x over previous
//
#include <hip/hip_runtime.h>

// RGCN basis-decomposition layer, MI355X (gfx950).
//
// Algebra (torch-.view quirk folded out):
//   U[n][k*4+b] = sum_{j<8} h[n][k*8+j] * w_comp[j][b]     (fold, [N,128], bf16)
//   S[r][d]     = sum_{e: dst=d, et=r} U[src_e]            (bucketed aggregate)
//   out         = relu(sum_r S[r] @ Bv[r] + bias)          (bf16 MFMA GEMM, K=8*128)
//
// R5: B pre-packed into per-wave MFMA fragment order Bp[ct][r][ks][lane][8]
// so every B load is a fully-coalesced 1KB wave-load (R4's Bt reads had 2KB
// lane stride -> 4x sector amplification -> L2-request-bound at 54us).
// Aggregate: next bucket int4 prefetched (software pipeline).

#define N_NODES  20000
#define N_EDGES  320000
#define IN_DIM   256
#define OUT_DIM  256
#define NUM_RELS 8
#define KDIM     128
#define M_PAD    20032          // 626 * 32
#define CAP      96             // bucket capacity per dst node (avg deg 16)

#define FOLD_BLOCKS 2500        // N_NODES*32 / 256
#define FILL_BLOCKS 1250        // N_EDGES / 256
#define BP_BLOCKS   128         // 8ct*8r*8ks*64lane fragments / 256 thr

typedef __attribute__((ext_vector_type(8)))  short short8;
typedef __attribute__((ext_vector_type(16))) float float16v;

static __device__ __forceinline__ unsigned f2bf_rne(float x) {
    unsigned u = __float_as_uint(x);
    return (u + 0x7fffu + ((u >> 16) & 1u)) >> 16;
}
static __device__ __forceinline__ float bf2f(unsigned b) {
    return __uint_as_float(b << 16);
}

// ----------------------------------------------------------------- prep ----
// blockIdx [0, FOLD)           : fold h -> U (bf16)
// blockIdx [FOLD, FOLD+FILL)   : bucket-fill edges by dst
// blockIdx [FOLD+FILL, ...+BP) : basis -> Bp (bf16, MFMA-fragment order)
__global__ __launch_bounds__(256)
void prep_kernel(const float* __restrict__ h, const float* __restrict__ w_comp,
                 unsigned short* __restrict__ U,
                 const int* __restrict__ src, const int* __restrict__ dst,
                 const int* __restrict__ et,
                 int* __restrict__ cnt, int* __restrict__ bucket,
                 const float* __restrict__ basis, unsigned short* __restrict__ Bp) {
    int b = blockIdx.x;
    int t = threadIdx.x;
    if (b < FOLD_BLOCKS) {
        // thread computes U[n][k*4 .. k*4+3]
        int gid = b * 256 + t;                 // over N_NODES*32
        int n = gid >> 5, k = gid & 31;
        const float* hp = h + (size_t)n * IN_DIM + k * 8;
        float4 h0 = *(const float4*)hp;
        float4 h1 = *(const float4*)(hp + 4);
        float hv[8] = {h0.x, h0.y, h0.z, h0.w, h1.x, h1.y, h1.z, h1.w};
        float a0 = 0.f, a1 = 0.f, a2 = 0.f, a3 = 0.f;
#pragma unroll
        for (int j = 0; j < 8; ++j) {
            float hj = hv[j];
            a0 += hj * w_comp[j * 4 + 0];
            a1 += hj * w_comp[j * 4 + 1];
            a2 += hj * w_comp[j * 4 + 2];
            a3 += hj * w_comp[j * 4 + 3];
        }
        uint2 p;
        p.x = f2bf_rne(a0) | (f2bf_rne(a1) << 16);
        p.y = f2bf_rne(a2) | (f2bf_rne(a3) << 16);
        *(uint2*)(U + ((size_t)n << 7) + k * 4) = p;
    } else if (b < FOLD_BLOCKS + FILL_BLOCKS) {
        int e = (b - FOLD_BLOCKS) * 256 + t;
        int d = dst[e];
        int p = atomicAdd(&cnt[d], 1);
        if (p < CAP) bucket[(size_t)d * CAP + p] = src[e] | (et[e] << 16);
    } else {
        // one B fragment (16B) per thread, MFMA fragment order:
        // Bp[((ct*8+r)*8+ks)*64 + lane][j] = bf16(basis[(r*128+ks*16+(lane>>5)*8+j)*256 + ct*32+(lane&31)])
        int frag = (b - FOLD_BLOCKS - FILL_BLOCKS) * 256 + t;   // [0, 32768)
        int lane = frag & 63;
        int ks   = (frag >> 6) & 7;
        int r    = (frag >> 9) & 7;
        int ct   = frag >> 12;
        int o  = ct * 32 + (lane & 31);
        int kb = r * 128 + ks * 16 + (lane >> 5) * 8;
        const float* bsp = basis + (size_t)kb * 256 + o;
        unsigned v[8];
#pragma unroll
        for (int j = 0; j < 8; ++j) v[j] = f2bf_rne(bsp[(size_t)j * 256]);
        uint4 p;
        p.x = v[0] | (v[1] << 16);
        p.y = v[2] | (v[3] << 16);
        p.z = v[4] | (v[5] << 16);
        p.w = v[6] | (v[7] << 16);
        *(uint4*)(Bp + (size_t)frag * 8) = p;
    }
}

// ------------------------------------------------------------ aggregate ----
// One wave per dst node; bucket read int4 with next-batch prefetch.
// 8 relation rows accumulated fp32 in registers, written bf16.
__global__ __launch_bounds__(256)
void aggregate_kernel(const unsigned short* __restrict__ U,
                      const int* __restrict__ cnt,
                      const int* __restrict__ bucket,
                      unsigned int* __restrict__ S) {  // S as uint (2 bf16)
    int wid  = threadIdx.x >> 6;
    int lane = threadIdx.x & 63;
    int d = blockIdx.x * 4 + wid;          // < 20032
    float2 acc[NUM_RELS];
#pragma unroll
    for (int r = 0; r < NUM_RELS; ++r) { acc[r].x = 0.f; acc[r].y = 0.f; }

    if (d < N_NODES) {
        int n = cnt[d];
        if (n > CAP) n = CAP;
        const int4* bp4 = (const int4*)(bucket + (size_t)d * CAP);
        int4 e4 = bp4[0];
        for (int i = 0; i < n; i += 4) {
            int4 cur = e4;
            e4 = bp4[(i >> 2) + 1];        // prefetch (bucket has +16B slack)
            int m = n - i;
            int es[4] = {cur.x, cur.y, cur.z, cur.w};
#pragma unroll
            for (int j = 0; j < 4; ++j) {
                if (j < m) {
                    int e = es[j];
                    int s = e & 0xffff;
                    int r = __builtin_amdgcn_readfirstlane(e >> 16);
                    unsigned u = *(const unsigned*)(U + ((size_t)s << 7) + lane * 2);
                    float fx = bf2f(u & 0xffffu), fy = bf2f(u >> 16);
                    switch (r) {
                        case 0: acc[0].x += fx; acc[0].y += fy; break;
                        case 1: acc[1].x += fx; acc[1].y += fy; break;
                        case 2: acc[2].x += fx; acc[2].y += fy; break;
                        case 3: acc[3].x += fx; acc[3].y += fy; break;
                        case 4: acc[4].x += fx; acc[4].y += fy; break;
                        case 5: acc[5].x += fx; acc[5].y += fy; break;
                        case 6: acc[6].x += fx; acc[6].y += fy; break;
                        default: acc[7].x += fx; acc[7].y += fy; break;
                    }
                }
            }
        }
    }
#pragma unroll
    for (int r = 0; r < NUM_RELS; ++r) {
        unsigned p = f2bf_rne(acc[r].x) | (f2bf_rne(acc[r].y) << 16);
        S[(((size_t)r * M_PAD + d) << 6) + lane] = p;
    }
}

// ----------------------------------------------------------------- gemm ----
// out[n][o] = relu(sum_{r,k} S[r][n][k] * Bp-frag + bias[o])
// 512 thr = 8 waves; C tile 32 rows x 256 cols; wave w -> one 32x32 MFMA
// tile at cols w*32. Grid 626. A staged once via LDS (VGPR prefetch of the
// next relation); B fragments read coalesced from packed Bp (L2-resident).
__global__ __launch_bounds__(512)
void gemm_kernel(const unsigned short* __restrict__ S,
                 const unsigned short* __restrict__ Bp,
                 const float* __restrict__ bias,
                 float* __restrict__ out) {
    __shared__ unsigned short At[32][136];
    int t = threadIdx.x;
    int w = t >> 6, lane = t & 63;
    int ln = lane & 31, hi = lane >> 5;
    int n0 = blockIdx.x * 32;
    int c0 = w * 32;

    int srow = t >> 4, sq = t & 15;        // staging: 512 x 16B = 32 rows x 256B
    const unsigned short* sbase = S + (((size_t)n0 + srow) << 7) + sq * 8;
    uint4 pre = *(const uint4*)sbase;      // r=0 A-tile fragment

    float16v acc = {};

    for (int r = 0; r < NUM_RELS; ++r) {
        if (r > 0) __syncthreads();        // prev iter's LDS reads complete
        *(uint4*)&At[srow][sq * 8] = pre;
        __syncthreads();
        if (r + 1 < NUM_RELS)
            pre = *(const uint4*)(sbase + (((size_t)(r + 1) * M_PAD) << 7));
        // packed B: fragment base for (ct=w, r, ks), 1KB contiguous per wave
        const unsigned short* bpr = Bp + (((size_t)(w * 8 + r) * 8) << 9) + lane * 8;
#pragma unroll
        for (int ks = 0; ks < 8; ++ks) {
            short8 a  = *(const short8*)&At[ln][ks * 16 + hi * 8];
            short8 bo = *(const short8*)(bpr + (ks << 9));
            acc = __builtin_amdgcn_mfma_f32_32x32x16_bf16(a, bo, acc, 0, 0, 0);
        }
    }

    // epilogue: C/D layout col=lane&31, row=(reg&3)+8*(reg>>2)+4*(lane>>5)
    float bs = bias[c0 + ln];
#pragma unroll
    for (int reg = 0; reg < 16; ++reg) {
        int row = (reg & 3) + 8 * (reg >> 2) + 4 * hi;
        int n = n0 + row;
        if (n < N_NODES)
            out[(size_t)n * OUT_DIM + c0 + ln] = fmaxf(acc[reg] + bs, 0.f);
    }
}

// --------------------------------------------------------------- launch ----
extern "C" void kernel_launch(void* const* d_in, const int* in_sizes, int n_in,
                              void* d_out, int out_size, void* d_ws, size_t ws_size,
                              hipStream_t stream) {
    const float* h      = (const float*)d_in[0];
    const float* basis  = (const float*)d_in[1];
    const float* w_comp = (const float*)d_in[2];
    const float* bias   = (const float*)d_in[3];
    const int*   src    = (const int*)d_in[4];
    const int*   dst    = (const int*)d_in[5];
    const int*   etype  = (const int*)d_in[6];
    float*       out    = (float*)d_out;

    char* ws = (char*)d_ws;
    size_t off = 0;
    unsigned short* U   = (unsigned short*)(ws + off); off += (size_t)N_NODES * KDIM * 2;          // 5.12 MB
    unsigned int*   S   = (unsigned int*)(ws + off);   off += (size_t)NUM_RELS * M_PAD * KDIM * 2; // 41.0 MB
    unsigned short* Bp  = (unsigned short*)(ws + off); off += (size_t)8 * 8 * 8 * 64 * 8 * 2;      // 0.52 MB
    int* cnt    = (int*)(ws + off); off += (size_t)M_PAD * 4;                                      // 80 KB
    int* bucket = (int*)(ws + off); off += ((size_t)M_PAD * CAP + 16) * 4;                         // 7.7 MB (+slack)

    hipMemsetAsync(cnt, 0, (size_t)N_NODES * 4, stream);

    prep_kernel<<<FOLD_BLOCKS + FILL_BLOCKS + BP_BLOCKS, 256, 0, stream>>>(
        h, w_comp, U, src, dst, etype, cnt, bucket, basis, Bp);

    aggregate_kernel<<<M_PAD / 4, 256, 0, stream>>>(U, cnt, bucket, S);

    gemm_kernel<<<M_PAD / 32, 512, 0, stream>>>((const unsigned short*)S, Bp, bias, out);
}